// Round 2
// baseline (22703.305 us; speedup 1.0000x reference)
//
#include <hip/hip_runtime.h>
#include <hip/hip_bf16.h>

#define D 128
#define NGRAPHS 64
#define NCLASSES 10

// -------- edge scatter: agg[dst] += x[src], 32 threads (= half wave) per edge --------
__global__ __launch_bounds__(256) void k_scatter(
    const float* __restrict__ x, const int* __restrict__ src,
    const int* __restrict__ dst, float* __restrict__ agg, int n_edges) {
  long long tid = (long long)blockIdx.x * blockDim.x + threadIdx.x;
  int c = (int)(tid & 31) * 4;     // float4 chunk within the 128-wide row
  int e = (int)(tid >> 5);
  if (e >= n_edges) return;
  int s = src[e];
  int d = dst[e];
  float4 v = *reinterpret_cast<const float4*>(x + (long long)s * D + c);
  float* o = agg + (long long)d * D + c;
  atomicAdd(o + 0, v.x);
  atomicAdd(o + 1, v.y);
  atomicAdd(o + 2, v.z);
  atomicAdd(o + 3, v.w);
}

// -------- fused dual GEMM: out = A1@W1 + A2@W2 + bias   (K=128 each, N=128) --------
#define BM 64
#define BK 32
__global__ __launch_bounds__(256) void k_gemm_dual(
    const float* __restrict__ A1, const float* __restrict__ A2,
    const float* __restrict__ W1, const float* __restrict__ W2,
    const float* __restrict__ bias, float* __restrict__ outp, int M) {
  __shared__ float As[BM][BK + 4];   // +4 keeps 16B alignment, breaks pow2 stride
  __shared__ float Ws[BK][D];
  int tid = threadIdx.x;
  int row0 = blockIdx.x * BM;
  int colg = (tid & 31) * 4;         // 4 output cols
  int rowb = tid >> 5;               // base row 0..7; rows rowb + 8*i
  float acc[8][4];
  float4 bv = *reinterpret_cast<const float4*>(bias + colg);
  #pragma unroll
  for (int i = 0; i < 8; i++) { acc[i][0] = bv.x; acc[i][1] = bv.y; acc[i][2] = bv.z; acc[i][3] = bv.w; }

  #pragma unroll
  for (int pass = 0; pass < 2; pass++) {
    const float* A = pass ? A2 : A1;
    const float* W = pass ? W2 : W1;
    for (int k0 = 0; k0 < D; k0 += BK) {
      // stage A tile (64x32): 512 float4, 2 per thread
      #pragma unroll
      for (int l = 0; l < 2; l++) {
        int f = tid + l * 256;
        int r = f >> 3;
        int kc = (f & 7) * 4;
        int rr = row0 + r; if (rr >= M) rr = M - 1;   // clamp; garbage rows never stored
        float4 v = *reinterpret_cast<const float4*>(A + (long long)rr * D + k0 + kc);
        As[r][kc] = v.x; As[r][kc + 1] = v.y; As[r][kc + 2] = v.z; As[r][kc + 3] = v.w;
      }
      // stage W tile (32x128): 1024 float4, 4 per thread
      #pragma unroll
      for (int l = 0; l < 4; l++) {
        int f = tid + l * 256;
        int r = f >> 5;
        int kc = (f & 31) * 4;
        *reinterpret_cast<float4*>(&Ws[r][kc]) =
            *reinterpret_cast<const float4*>(W + (k0 + r) * D + kc);
      }
      __syncthreads();
      #pragma unroll
      for (int k = 0; k < BK; k += 4) {
        float4 a4[8];
        #pragma unroll
        for (int i = 0; i < 8; i++)
          a4[i] = *reinterpret_cast<const float4*>(&As[rowb + i * 8][k]);
        #pragma unroll
        for (int kk = 0; kk < 4; kk++) {
          float4 wv = *reinterpret_cast<const float4*>(&Ws[k + kk][colg]);
          #pragma unroll
          for (int i = 0; i < 8; i++) {
            float a = (kk == 0) ? a4[i].x : (kk == 1) ? a4[i].y : (kk == 2) ? a4[i].z : a4[i].w;
            acc[i][0] += a * wv.x;
            acc[i][1] += a * wv.y;
            acc[i][2] += a * wv.z;
            acc[i][3] += a * wv.w;
          }
        }
      }
      __syncthreads();
    }
  }
  #pragma unroll
  for (int i = 0; i < 8; i++) {
    int r = row0 + rowb + i * 8;
    if (r < M)
      *reinterpret_cast<float4*>(outp + (long long)r * D + colg) =
          make_float4(acc[i][0], acc[i][1], acc[i][2], acc[i][3]);
  }
}

// -------- mean pool, stage 1: batch is SORTED -> run-length partial sums --------
#define CHUNK 256
__global__ __launch_bounds__(256) void k_pool(
    const float* __restrict__ x, const int* __restrict__ batch,
    float* __restrict__ pooled, int n_nodes) {
  int col = threadIdx.x & 127;
  int sub = threadIdx.x >> 7;         // 0..1
  int n0 = blockIdx.x * CHUNK;
  int nend = min(n0 + CHUNK, n_nodes);
  float sum = 0.f; int cur = -1;
  for (int n = n0 + sub; n < nend; n += 2) {
    int g = batch[n];
    if (g != cur) {
      if (cur >= 0) atomicAdd(&pooled[cur * D + col], sum);
      sum = 0.f; cur = g;
    }
    sum += x[(long long)n * D + col];
  }
  if (cur >= 0) atomicAdd(&pooled[cur * D + col], sum);
}

__global__ __launch_bounds__(256) void k_count(
    const int* __restrict__ batch, int* __restrict__ counts, int n) {
  int i = blockIdx.x * blockDim.x + threadIdx.x;
  if (i < n) atomicAdd(&counts[batch[i]], 1);
}

// -------- head: divide by counts, 64x128 @ 128x10 + bias, log_softmax --------
__global__ void k_head(const float* __restrict__ pooled, const int* __restrict__ counts,
                       const float* __restrict__ W_fc, const float* __restrict__ b_fc,
                       float* __restrict__ outp) {
  int g = threadIdx.x;
  if (g >= NGRAPHS) return;
  float inv = 1.0f / fmaxf((float)counts[g], 1.0f);
  float logits[NCLASSES];
  #pragma unroll
  for (int j = 0; j < NCLASSES; j++) logits[j] = b_fc[j];
  for (int k = 0; k < D; k++) {
    float p = pooled[g * D + k] * inv;
    #pragma unroll
    for (int j = 0; j < NCLASSES; j++) logits[j] += p * W_fc[k * NCLASSES + j];
  }
  float m = logits[0];
  #pragma unroll
  for (int j = 1; j < NCLASSES; j++) m = fmaxf(m, logits[j]);
  float s = 0.f;
  #pragma unroll
  for (int j = 0; j < NCLASSES; j++) s += expf(logits[j] - m);
  float lse = m + logf(s);
  #pragma unroll
  for (int j = 0; j < NCLASSES; j++) outp[g * NCLASSES + j] = logits[j] - lse;
}

extern "C" void kernel_launch(void* const* d_in, const int* in_sizes, int n_in,
                              void* d_out, int out_size, void* d_ws, size_t ws_size,
                              hipStream_t stream) {
  const float* x      = (const float*)d_in[0];
  const int*   ei     = (const int*)d_in[1];
  const int*   batch  = (const int*)d_in[2];
  const float* W_rel  = (const float*)d_in[3];
  const float* W_root = (const float*)d_in[4];
  const float* b_rel  = (const float*)d_in[5];
  const float* W_fc   = (const float*)d_in[6];
  const float* b_fc   = (const float*)d_in[7];
  float* outp = (float*)d_out;

  int n_nodes = in_sizes[0] / D;
  int n_edges = in_sizes[1] / 2;
  const int* src = ei;
  const int* dst = ei + n_edges;

  char* ws = (char*)d_ws;
  size_t fbytes = (size_t)n_nodes * D * sizeof(float);
  float* agg    = (float*)(ws);
  float* xa     = (float*)(ws + fbytes);
  float* xb     = (float*)(ws + 2 * fbytes);
  float* pooled = (float*)(ws + 3 * fbytes);
  int*   counts = (int*)(ws + 3 * fbytes + (size_t)NGRAPHS * D * sizeof(float));

  const float* xc = x;
  float* xn = xa;
  for (int l = 0; l < 3; l++) {
    hipMemsetAsync(agg, 0, fbytes, stream);
    int sthreads = n_edges * 32;
    k_scatter<<<(sthreads + 255) / 256, 256, 0, stream>>>(xc, src, dst, agg, n_edges);
    k_gemm_dual<<<(n_nodes + BM - 1) / BM, 256, 0, stream>>>(
        agg, xc, W_rel + (size_t)l * D * D, W_root + (size_t)l * D * D,
        b_rel + (size_t)l * D, xn, n_nodes);
    xc = xn;
    xn = (xc == xa) ? xb : xa;
  }

  hipMemsetAsync(pooled, 0, (size_t)NGRAPHS * D * sizeof(float), stream);
  hipMemsetAsync(counts, 0, (size_t)NGRAPHS * sizeof(int), stream);
  k_pool<<<(n_nodes + CHUNK - 1) / CHUNK, 256, 0, stream>>>(xc, batch, pooled, n_nodes);
  k_count<<<(n_nodes + 255) / 256, 256, 0, stream>>>(batch, counts, n_nodes);
  k_head<<<1, 64, 0, stream>>>(pooled, counts, W_fc, b_fc, outp);
}

// Round 3
// 1377.167 us; speedup vs baseline: 16.4855x; 16.4855x over previous
//
#include <hip/hip_runtime.h>
#include <hip/hip_bf16.h>

#define D 128
#define NGRAPHS 64
#define NCLASSES 10

// ================= CSR build =================
__global__ __launch_bounds__(256) void k_hist(const int* __restrict__ dst,
                                              int* __restrict__ deg, int n) {
  int i = blockIdx.x * 256 + threadIdx.x;
  if (i < n) atomicAdd(&deg[dst[i]], 1);
}

// exclusive block scan: 1024 elems/block (256 thr x 4). Also used for bsum pass.
__global__ __launch_bounds__(256) void k_scan_block(
    const int* __restrict__ in, int* __restrict__ out,
    int* __restrict__ bsum, int n) {
  __shared__ int sh[256];
  int t = threadIdx.x;
  int base = blockIdx.x * 1024 + t * 4;
  int v0 = (base + 0 < n) ? in[base + 0] : 0;
  int v1 = (base + 1 < n) ? in[base + 1] : 0;
  int v2 = (base + 2 < n) ? in[base + 2] : 0;
  int v3 = (base + 3 < n) ? in[base + 3] : 0;
  int l1 = v0 + v1, l2 = l1 + v2, l3 = l2 + v3;
  sh[t] = l3;
  __syncthreads();
  for (int off = 1; off < 256; off <<= 1) {
    int y = (t >= off) ? sh[t - off] : 0;
    __syncthreads();
    sh[t] += y;
    __syncthreads();
  }
  int excl = sh[t] - l3;
  if (base + 0 < n) out[base + 0] = excl;
  if (base + 1 < n) out[base + 1] = excl + v0;
  if (base + 2 < n) out[base + 2] = excl + l1;
  if (base + 3 < n) out[base + 3] = excl + l2;
  if (t == 255 && bsum) bsum[blockIdx.x] = sh[255];
}

__global__ __launch_bounds__(256) void k_scan_add(
    int* __restrict__ rowptr, int* __restrict__ cursor,
    const int* __restrict__ bscan, int n) {
  int i = blockIdx.x * 256 + threadIdx.x;
  if (i < n) {
    int r = rowptr[i] + bscan[i >> 10];
    rowptr[i] = r;
    cursor[i] = r;
  }
}

__global__ __launch_bounds__(256) void k_fill(
    const int* __restrict__ src, const int* __restrict__ dst,
    int* __restrict__ cursor, int* __restrict__ eidx, int n) {
  int e = blockIdx.x * 256 + threadIdx.x;
  if (e < n) {
    int slot = atomicAdd(&cursor[dst[e]], 1);
    eidx[slot] = src[e];
  }
}

// ================= gather aggregation: agg[n] = sum_{e: dst=n} x[src_e] =================
__global__ __launch_bounds__(256) void k_gather(
    const float* __restrict__ x, const int* __restrict__ rowptr,
    const int* __restrict__ deg, const int* __restrict__ eidx,
    float* __restrict__ agg, int n_nodes) {
  int tid = threadIdx.x;
  int n = blockIdx.x * 8 + (tid >> 5);
  int c = (tid & 31) * 4;
  if (n >= n_nodes) return;
  int beg = rowptr[n];
  int dn = deg[n];
  float4 acc = make_float4(0.f, 0.f, 0.f, 0.f);
  for (int i = 0; i < dn; i++) {
    int s = eidx[beg + i];
    float4 v = *reinterpret_cast<const float4*>(x + (size_t)s * D + c);
    acc.x += v.x; acc.y += v.y; acc.z += v.z; acc.w += v.w;
  }
  *reinterpret_cast<float4*>(agg + (size_t)n * D + c) = acc;
}

// ================= fused dual GEMM: out = A1@W1 + A2@W2 + bias =================
#define BM 64
#define BK 32
__global__ __launch_bounds__(256) void k_gemm_dual(
    const float* __restrict__ A1, const float* __restrict__ A2,
    const float* __restrict__ W1, const float* __restrict__ W2,
    const float* __restrict__ bias, float* __restrict__ outp, int M) {
  __shared__ float As[BM][BK + 4];
  __shared__ float Ws[BK][D];
  int tid = threadIdx.x;
  int row0 = blockIdx.x * BM;
  int colg = (tid & 31) * 4;
  int rowb = tid >> 5;
  float acc[8][4];
  float4 bv = *reinterpret_cast<const float4*>(bias + colg);
  #pragma unroll
  for (int i = 0; i < 8; i++) { acc[i][0] = bv.x; acc[i][1] = bv.y; acc[i][2] = bv.z; acc[i][3] = bv.w; }

  #pragma unroll 1   // do NOT unroll: full unroll spilled to scratch (round-2 rocprof: 10 GB traffic)
  for (int pass = 0; pass < 2; pass++) {
    const float* A = pass ? A2 : A1;
    const float* W = pass ? W2 : W1;
    #pragma unroll 1
    for (int k0 = 0; k0 < D; k0 += BK) {
      #pragma unroll
      for (int l = 0; l < 2; l++) {
        int f = tid + l * 256;
        int r = f >> 3;
        int kc = (f & 7) * 4;
        int rr = row0 + r; if (rr >= M) rr = M - 1;
        float4 v = *reinterpret_cast<const float4*>(A + (size_t)rr * D + k0 + kc);
        As[r][kc] = v.x; As[r][kc + 1] = v.y; As[r][kc + 2] = v.z; As[r][kc + 3] = v.w;
      }
      #pragma unroll
      for (int l = 0; l < 4; l++) {
        int f = tid + l * 256;
        int r = f >> 5;
        int kc = (f & 31) * 4;
        *reinterpret_cast<float4*>(&Ws[r][kc]) =
            *reinterpret_cast<const float4*>(W + (k0 + r) * D + kc);
      }
      __syncthreads();
      #pragma unroll 2   // bounded: keeps live set ~110 VGPRs
      for (int k = 0; k < BK; k += 4) {
        float4 a4[8];
        #pragma unroll
        for (int i = 0; i < 8; i++)
          a4[i] = *reinterpret_cast<const float4*>(&As[rowb + i * 8][k]);
        #pragma unroll
        for (int kk = 0; kk < 4; kk++) {
          float4 wv = *reinterpret_cast<const float4*>(&Ws[k + kk][colg]);
          #pragma unroll
          for (int i = 0; i < 8; i++) {
            float a = (kk == 0) ? a4[i].x : (kk == 1) ? a4[i].y : (kk == 2) ? a4[i].z : a4[i].w;
            acc[i][0] += a * wv.x;
            acc[i][1] += a * wv.y;
            acc[i][2] += a * wv.z;
            acc[i][3] += a * wv.w;
          }
        }
      }
      __syncthreads();
    }
  }
  #pragma unroll
  for (int i = 0; i < 8; i++) {
    int r = row0 + rowb + i * 8;
    if (r < M)
      *reinterpret_cast<float4*>(outp + (size_t)r * D + colg) =
          make_float4(acc[i][0], acc[i][1], acc[i][2], acc[i][3]);
  }
}

// ================= mean pool (batch sorted) =================
#define CHUNK 256
__global__ __launch_bounds__(256) void k_pool(
    const float* __restrict__ x, const int* __restrict__ batch,
    float* __restrict__ pooled, int n_nodes) {
  int col = threadIdx.x & 127;
  int sub = threadIdx.x >> 7;
  int n0 = blockIdx.x * CHUNK;
  int nend = min(n0 + CHUNK, n_nodes);
  float sum = 0.f; int cur = -1;
  for (int n = n0 + sub; n < nend; n += 2) {
    int g = batch[n];
    if (g != cur) {
      if (cur >= 0) atomicAdd(&pooled[cur * D + col], sum);
      sum = 0.f; cur = g;
    }
    sum += x[(size_t)n * D + col];
  }
  if (cur >= 0) atomicAdd(&pooled[cur * D + col], sum);
}

__global__ __launch_bounds__(256) void k_count(
    const int* __restrict__ batch, int* __restrict__ counts, int n) {
  int i = blockIdx.x * blockDim.x + threadIdx.x;
  if (i < n) atomicAdd(&counts[batch[i]], 1);
}

// ================= head =================
__global__ void k_head(const float* __restrict__ pooled, const int* __restrict__ counts,
                       const float* __restrict__ W_fc, const float* __restrict__ b_fc,
                       float* __restrict__ outp) {
  int g = threadIdx.x;
  if (g >= NGRAPHS) return;
  float inv = 1.0f / fmaxf((float)counts[g], 1.0f);
  float logits[NCLASSES];
  #pragma unroll
  for (int j = 0; j < NCLASSES; j++) logits[j] = b_fc[j];
  for (int k = 0; k < D; k++) {
    float p = pooled[g * D + k] * inv;
    #pragma unroll
    for (int j = 0; j < NCLASSES; j++) logits[j] += p * W_fc[k * NCLASSES + j];
  }
  float m = logits[0];
  #pragma unroll
  for (int j = 1; j < NCLASSES; j++) m = fmaxf(m, logits[j]);
  float s = 0.f;
  #pragma unroll
  for (int j = 0; j < NCLASSES; j++) s += expf(logits[j] - m);
  float lse = m + logf(s);
  #pragma unroll
  for (int j = 0; j < NCLASSES; j++) outp[g * NCLASSES + j] = logits[j] - lse;
}

extern "C" void kernel_launch(void* const* d_in, const int* in_sizes, int n_in,
                              void* d_out, int out_size, void* d_ws, size_t ws_size,
                              hipStream_t stream) {
  const float* x      = (const float*)d_in[0];
  const int*   ei     = (const int*)d_in[1];
  const int*   batch  = (const int*)d_in[2];
  const float* W_rel  = (const float*)d_in[3];
  const float* W_root = (const float*)d_in[4];
  const float* b_rel  = (const float*)d_in[5];
  const float* W_fc   = (const float*)d_in[6];
  const float* b_fc   = (const float*)d_in[7];
  float* outp = (float*)d_out;

  int n_nodes = in_sizes[0] / D;
  int n_edges = in_sizes[1] / 2;
  const int* src = ei;
  const int* dst = ei + n_edges;

  char* ws = (char*)d_ws;
  size_t fb = (size_t)n_nodes * D * sizeof(float);
  size_t nb = (size_t)n_nodes * sizeof(int);
  float* agg    = (float*)(ws);
  float* xa     = (float*)(ws + fb);
  float* xb     = (float*)(ws + 2 * fb);
  char*  p      = ws + 3 * fb;
  int* deg      = (int*)(p);             p += nb;
  int* rowptr   = (int*)(p);             p += nb;
  int* cursor   = (int*)(p);             p += nb;
  int* bsum     = (int*)(p);             p += 1024 * sizeof(int);
  int* eidx     = (int*)(p);             p += (size_t)n_edges * sizeof(int);
  float* pooled = (float*)(p);           p += (size_t)NGRAPHS * D * sizeof(float);
  int* counts   = (int*)(p);

  // ---- CSR build (per launch; inputs are re-poisoned each call) ----
  int eblk = (n_edges + 255) / 256;
  int sblk = (n_nodes + 1023) / 1024;
  hipMemsetAsync(deg, 0, nb, stream);
  k_hist<<<eblk, 256, 0, stream>>>(dst, deg, n_edges);
  k_scan_block<<<sblk, 256, 0, stream>>>(deg, rowptr, bsum, n_nodes);
  k_scan_block<<<1, 256, 0, stream>>>(bsum, bsum, nullptr, sblk);
  k_scan_add<<<(n_nodes + 255) / 256, 256, 0, stream>>>(rowptr, cursor, bsum, n_nodes);
  k_fill<<<eblk, 256, 0, stream>>>(src, dst, cursor, eidx, n_edges);

  // ---- 3 GraphConv layers ----
  const float* xc = x;
  float* xn = xa;
  for (int l = 0; l < 3; l++) {
    k_gather<<<(n_nodes + 7) / 8, 256, 0, stream>>>(xc, rowptr, deg, eidx, agg, n_nodes);
    k_gemm_dual<<<(n_nodes + BM - 1) / BM, 256, 0, stream>>>(
        agg, xc, W_rel + (size_t)l * D * D, W_root + (size_t)l * D * D,
        b_rel + (size_t)l * D, xn, n_nodes);
    xc = xn;
    xn = (xc == xa) ? xb : xa;
  }

  // ---- pool + head ----
  hipMemsetAsync(pooled, 0, (size_t)NGRAPHS * D * sizeof(float), stream);
  hipMemsetAsync(counts, 0, (size_t)NGRAPHS * sizeof(int), stream);
  k_pool<<<(n_nodes + CHUNK - 1) / CHUNK, 256, 0, stream>>>(xc, batch, pooled, n_nodes);
  k_count<<<(n_nodes + 255) / 256, 256, 0, stream>>>(batch, counts, n_nodes);
  k_head<<<1, 64, 0, stream>>>(pooled, counts, W_fc, b_fc, outp);
}

// Round 4
// 985.151 us; speedup vs baseline: 23.0455x; 1.3979x over previous
//
#include <hip/hip_runtime.h>
#include <hip/hip_bf16.h>

#define D 128
#define NGRAPHS 64
#define NCLASSES 10

// ================= CSR build =================
__global__ __launch_bounds__(256) void k_hist(const int* __restrict__ dst,
                                              int* __restrict__ deg, int n) {
  int i = blockIdx.x * 256 + threadIdx.x;
  if (i < n) atomicAdd(&deg[dst[i]], 1);
}

// exclusive block scan: 1024 elems/block (256 thr x 4). Also used for bsum pass.
__global__ __launch_bounds__(256) void k_scan_block(
    const int* __restrict__ in, int* __restrict__ out,
    int* __restrict__ bsum, int n) {
  __shared__ int sh[256];
  int t = threadIdx.x;
  int base = blockIdx.x * 1024 + t * 4;
  int v0 = (base + 0 < n) ? in[base + 0] : 0;
  int v1 = (base + 1 < n) ? in[base + 1] : 0;
  int v2 = (base + 2 < n) ? in[base + 2] : 0;
  int v3 = (base + 3 < n) ? in[base + 3] : 0;
  int l1 = v0 + v1, l2 = l1 + v2, l3 = l2 + v3;
  sh[t] = l3;
  __syncthreads();
  for (int off = 1; off < 256; off <<= 1) {
    int y = (t >= off) ? sh[t - off] : 0;
    __syncthreads();
    sh[t] += y;
    __syncthreads();
  }
  int excl = sh[t] - l3;
  if (base + 0 < n) out[base + 0] = excl;
  if (base + 1 < n) out[base + 1] = excl + v0;
  if (base + 2 < n) out[base + 2] = excl + l1;
  if (base + 3 < n) out[base + 3] = excl + l2;
  if (t == 255 && bsum) bsum[blockIdx.x] = sh[255];
}

__global__ __launch_bounds__(256) void k_scan_add(
    int* __restrict__ rowptr, int* __restrict__ cursor,
    const int* __restrict__ bscan, int n) {
  int i = blockIdx.x * 256 + threadIdx.x;
  if (i < n) {
    int r = rowptr[i] + bscan[i >> 10];
    rowptr[i] = r;
    cursor[i] = r;
  }
}

__global__ __launch_bounds__(256) void k_fill(
    const int* __restrict__ src, const int* __restrict__ dst,
    int* __restrict__ cursor, int* __restrict__ eidx, int n) {
  int e = blockIdx.x * 256 + threadIdx.x;
  if (e < n) {
    int slot = atomicAdd(&cursor[dst[e]], 1);
    eidx[slot] = src[e];
  }
}

// ================= gather aggregation: agg[n] = sum_{e: dst=n} x[src_e] =================
__global__ __launch_bounds__(256) void k_gather(
    const float* __restrict__ x, const int* __restrict__ rowptr,
    const int* __restrict__ deg, const int* __restrict__ eidx,
    float* __restrict__ agg, int n_nodes) {
  int tid = threadIdx.x;
  int n = blockIdx.x * 8 + (tid >> 5);
  int c = (tid & 31) * 4;
  if (n >= n_nodes) return;
  int beg = rowptr[n];
  int dn = deg[n];
  float4 acc = make_float4(0.f, 0.f, 0.f, 0.f);
  for (int i = 0; i < dn; i++) {
    int s = eidx[beg + i];
    float4 v = *reinterpret_cast<const float4*>(x + (size_t)s * D + c);
    acc.x += v.x; acc.y += v.y; acc.z += v.z; acc.w += v.w;
  }
  *reinterpret_cast<float4*>(agg + (size_t)n * D + c) = acc;
}

// ================= fused dual GEMM: out = A1@W1 + A2@W2 + bias =================
#define BM 64
#define BK 32
__global__ __launch_bounds__(256) void k_gemm_dual(
    const float* __restrict__ A1, const float* __restrict__ A2,
    const float* __restrict__ W1, const float* __restrict__ W2,
    const float* __restrict__ bias, float* __restrict__ outp, int M) {
  __shared__ float As[BM][BK + 4];
  __shared__ float Ws[BK][D];
  int tid = threadIdx.x;
  int row0 = blockIdx.x * BM;
  int colg = (tid & 31) * 4;
  int rowb = tid >> 5;
  float acc[8][4];
  float4 bv = *reinterpret_cast<const float4*>(bias + colg);
  #pragma unroll
  for (int i = 0; i < 8; i++) { acc[i][0] = bv.x; acc[i][1] = bv.y; acc[i][2] = bv.z; acc[i][3] = bv.w; }

  #pragma unroll 1   // do NOT unroll: full unroll spilled to scratch (round-2 rocprof: 10 GB traffic)
  for (int pass = 0; pass < 2; pass++) {
    const float* A = pass ? A2 : A1;
    const float* W = pass ? W2 : W1;
    #pragma unroll 1
    for (int k0 = 0; k0 < D; k0 += BK) {
      #pragma unroll
      for (int l = 0; l < 2; l++) {
        int f = tid + l * 256;
        int r = f >> 3;
        int kc = (f & 7) * 4;
        int rr = row0 + r; if (rr >= M) rr = M - 1;
        float4 v = *reinterpret_cast<const float4*>(A + (size_t)rr * D + k0 + kc);
        As[r][kc] = v.x; As[r][kc + 1] = v.y; As[r][kc + 2] = v.z; As[r][kc + 3] = v.w;
      }
      #pragma unroll
      for (int l = 0; l < 4; l++) {
        int f = tid + l * 256;
        int r = f >> 5;
        int kc = (f & 31) * 4;
        *reinterpret_cast<float4*>(&Ws[r][kc]) =
            *reinterpret_cast<const float4*>(W + (k0 + r) * D + kc);
      }
      __syncthreads();
      #pragma unroll 2   // bounded: keeps live set ~110 VGPRs
      for (int k = 0; k < BK; k += 4) {
        float4 a4[8];
        #pragma unroll
        for (int i = 0; i < 8; i++)
          a4[i] = *reinterpret_cast<const float4*>(&As[rowb + i * 8][k]);
        #pragma unroll
        for (int kk = 0; kk < 4; kk++) {
          float4 wv = *reinterpret_cast<const float4*>(&Ws[k + kk][colg]);
          #pragma unroll
          for (int i = 0; i < 8; i++) {
            float a = (kk == 0) ? a4[i].x : (kk == 1) ? a4[i].y : (kk == 2) ? a4[i].z : a4[i].w;
            acc[i][0] += a * wv.x;
            acc[i][1] += a * wv.y;
            acc[i][2] += a * wv.z;
            acc[i][3] += a * wv.w;
          }
        }
      }
      __syncthreads();
    }
  }
  #pragma unroll
  for (int i = 0; i < 8; i++) {
    int r = row0 + rowb + i * 8;
    if (r < M)
      *reinterpret_cast<float4*>(outp + (size_t)r * D + colg) =
          make_float4(acc[i][0], acc[i][1], acc[i][2], acc[i][3]);
  }
}

// ================= mean pool (batch sorted) =================
#define CHUNK 256
__global__ __launch_bounds__(256) void k_pool(
    const float* __restrict__ x, const int* __restrict__ batch,
    float* __restrict__ pooled, int n_nodes) {
  int col = threadIdx.x & 127;
  int sub = threadIdx.x >> 7;
  int n0 = blockIdx.x * CHUNK;
  int nend = min(n0 + CHUNK, n_nodes);
  float sum = 0.f; int cur = -1;
  for (int n = n0 + sub; n < nend; n += 2) {
    int g = batch[n];
    if (g != cur) {
      if (cur >= 0) atomicAdd(&pooled[cur * D + col], sum);
      sum = 0.f; cur = g;
    }
    sum += x[(size_t)n * D + col];
  }
  if (cur >= 0) atomicAdd(&pooled[cur * D + col], sum);
}

// ================= counts via sorted-boundary scan (replaces atomic histogram) =================
__global__ __launch_bounds__(256) void k_bounds(
    const int* __restrict__ batch, int* __restrict__ start, int n) {
  int i = blockIdx.x * 256 + threadIdx.x;
  if (i >= n) return;
  int g = batch[i];
  if (i == 0 || batch[i - 1] != g) start[g] = i;
}

__global__ void k_fin_counts(const int* __restrict__ start,
                             int* __restrict__ counts, int n) {
  int g = threadIdx.x;
  if (g >= NGRAPHS) return;
  int s = start[g];
  int c = 0;
  if (s >= 0) {
    int e = n;
    for (int h = g + 1; h < NGRAPHS; h++)
      if (start[h] >= 0) { e = start[h]; break; }
    c = e - s;
  }
  counts[g] = c;
}

// ================= head =================
__global__ void k_head(const float* __restrict__ pooled, const int* __restrict__ counts,
                       const float* __restrict__ W_fc, const float* __restrict__ b_fc,
                       float* __restrict__ outp) {
  int g = threadIdx.x;
  if (g >= NGRAPHS) return;
  float inv = 1.0f / fmaxf((float)counts[g], 1.0f);
  float logits[NCLASSES];
  #pragma unroll
  for (int j = 0; j < NCLASSES; j++) logits[j] = b_fc[j];
  for (int k = 0; k < D; k++) {
    float p = pooled[g * D + k] * inv;
    #pragma unroll
    for (int j = 0; j < NCLASSES; j++) logits[j] += p * W_fc[k * NCLASSES + j];
  }
  float m = logits[0];
  #pragma unroll
  for (int j = 1; j < NCLASSES; j++) m = fmaxf(m, logits[j]);
  float s = 0.f;
  #pragma unroll
  for (int j = 0; j < NCLASSES; j++) s += expf(logits[j] - m);
  float lse = m + logf(s);
  #pragma unroll
  for (int j = 0; j < NCLASSES; j++) outp[g * NCLASSES + j] = logits[j] - lse;
}

extern "C" void kernel_launch(void* const* d_in, const int* in_sizes, int n_in,
                              void* d_out, int out_size, void* d_ws, size_t ws_size,
                              hipStream_t stream) {
  const float* x      = (const float*)d_in[0];
  const int*   ei     = (const int*)d_in[1];
  const int*   batch  = (const int*)d_in[2];
  const float* W_rel  = (const float*)d_in[3];
  const float* W_root = (const float*)d_in[4];
  const float* b_rel  = (const float*)d_in[5];
  const float* W_fc   = (const float*)d_in[6];
  const float* b_fc   = (const float*)d_in[7];
  float* outp = (float*)d_out;

  int n_nodes = in_sizes[0] / D;
  int n_edges = in_sizes[1] / 2;
  const int* src = ei;
  const int* dst = ei + n_edges;

  char* ws = (char*)d_ws;
  size_t fb = (size_t)n_nodes * D * sizeof(float);
  size_t nb = (size_t)n_nodes * sizeof(int);
  float* agg    = (float*)(ws);
  float* xa     = (float*)(ws + fb);
  float* xb     = (float*)(ws + 2 * fb);
  char*  p      = ws + 3 * fb;
  int* deg      = (int*)(p);             p += nb;
  int* rowptr   = (int*)(p);             p += nb;
  int* cursor   = (int*)(p);             p += nb;
  int* bsum     = (int*)(p);             p += 1024 * sizeof(int);
  int* eidx     = (int*)(p);             p += (size_t)n_edges * sizeof(int);
  float* pooled = (float*)(p);           p += (size_t)NGRAPHS * D * sizeof(float);
  int* gstart   = (int*)(p);             p += (size_t)NGRAPHS * sizeof(int);
  int* counts   = (int*)(p);

  // ---- CSR build (per launch; ws is re-poisoned each call) ----
  int eblk = (n_edges + 255) / 256;
  int sblk = (n_nodes + 1023) / 1024;
  hipMemsetAsync(deg, 0, nb, stream);
  k_hist<<<eblk, 256, 0, stream>>>(dst, deg, n_edges);
  k_scan_block<<<sblk, 256, 0, stream>>>(deg, rowptr, bsum, n_nodes);
  k_scan_block<<<1, 256, 0, stream>>>(bsum, bsum, nullptr, sblk);
  k_scan_add<<<(n_nodes + 255) / 256, 256, 0, stream>>>(rowptr, cursor, bsum, n_nodes);
  k_fill<<<eblk, 256, 0, stream>>>(src, dst, cursor, eidx, n_edges);

  // ---- 3 GraphConv layers ----
  const float* xc = x;
  float* xn = xa;
  for (int l = 0; l < 3; l++) {
    k_gather<<<(n_nodes + 7) / 8, 256, 0, stream>>>(xc, rowptr, deg, eidx, agg, n_nodes);
    k_gemm_dual<<<(n_nodes + BM - 1) / BM, 256, 0, stream>>>(
        agg, xc, W_rel + (size_t)l * D * D, W_root + (size_t)l * D * D,
        b_rel + (size_t)l * D, xn, n_nodes);
    xc = xn;
    xn = (xc == xa) ? xb : xa;
  }

  // ---- pool + head ----
  hipMemsetAsync(pooled, 0, (size_t)NGRAPHS * D * sizeof(float), stream);
  hipMemsetAsync(gstart, 0xFF, (size_t)NGRAPHS * sizeof(int), stream);  // start[g] = -1
  k_pool<<<(n_nodes + CHUNK - 1) / CHUNK, 256, 0, stream>>>(xc, batch, pooled, n_nodes);
  k_bounds<<<(n_nodes + 255) / 256, 256, 0, stream>>>(batch, gstart, n_nodes);
  k_fin_counts<<<1, 64, 0, stream>>>(gstart, counts, n_nodes);
  k_head<<<1, 64, 0, stream>>>(pooled, counts, W_fc, b_fc, outp);
}

// Round 5
// 669.192 us; speedup vs baseline: 33.9264x; 1.4721x over previous
//
#include <hip/hip_runtime.h>
#include <hip/hip_bf16.h>

#define D 128
#define NGRAPHS 64
#define NCLASSES 10

typedef unsigned short u16;
typedef unsigned int u32;
typedef __attribute__((ext_vector_type(8))) short bf16x8;
typedef __attribute__((ext_vector_type(4))) float f32x4;

__device__ __forceinline__ u16 rne_bf16(float f) {
  u32 u = __float_as_uint(f);
  u += 0x7FFFu + ((u >> 16) & 1u);
  return (u16)(u >> 16);
}
__device__ __forceinline__ float bf_lo(u32 u) { return __uint_as_float(u << 16); }
__device__ __forceinline__ float bf_hi(u32 u) { return __uint_as_float(u & 0xFFFF0000u); }

// ================= f32 -> bf16 cast of x =================
__global__ __launch_bounds__(256) void k_cast0(const float* __restrict__ x,
                                               u16* __restrict__ xb, long long n8) {
  long long i = (long long)blockIdx.x * 256 + threadIdx.x;
  if (i >= n8) return;
  const float4* xp = reinterpret_cast<const float4*>(x) + i * 2;
  float4 a = xp[0], b = xp[1];
  u32 w0 = rne_bf16(a.x) | ((u32)rne_bf16(a.y) << 16);
  u32 w1 = rne_bf16(a.z) | ((u32)rne_bf16(a.w) << 16);
  u32 w2 = rne_bf16(b.x) | ((u32)rne_bf16(b.y) << 16);
  u32 w3 = rne_bf16(b.z) | ((u32)rne_bf16(b.w) << 16);
  reinterpret_cast<uint4*>(xb)[i] = make_uint4(w0, w1, w2, w3);
}

// ================= W[k][c] (f32) -> Wt[c][k] (bf16), 6 matrices =================
__global__ __launch_bounds__(256) void k_prep_wt(const float* __restrict__ W_rel,
                                                 const float* __restrict__ W_root,
                                                 u16* __restrict__ Wt) {
  int id = blockIdx.x * 256 + threadIdx.x;
  if (id >= 6 * D * D) return;
  int col = id & 127;
  int k = (id >> 7) & 127;
  int m = id >> 14;
  const float* src = (m < 3) ? (W_rel + (size_t)m * D * D) : (W_root + (size_t)(m - 3) * D * D);
  Wt[(size_t)m * D * D + col * D + k] = rne_bf16(src[k * D + col]);
}

// ================= CSR build =================
__global__ __launch_bounds__(256) void k_hist(const int* __restrict__ dst,
                                              int* __restrict__ deg, int n) {
  int i = blockIdx.x * 256 + threadIdx.x;
  if (i < n) atomicAdd(&deg[dst[i]], 1);
}

__global__ __launch_bounds__(256) void k_scan_block(
    const int* __restrict__ in, int* __restrict__ out,
    int* __restrict__ bsum, int n) {
  __shared__ int sh[256];
  int t = threadIdx.x;
  int base = blockIdx.x * 1024 + t * 4;
  int v0 = (base + 0 < n) ? in[base + 0] : 0;
  int v1 = (base + 1 < n) ? in[base + 1] : 0;
  int v2 = (base + 2 < n) ? in[base + 2] : 0;
  int v3 = (base + 3 < n) ? in[base + 3] : 0;
  int l1 = v0 + v1, l2 = l1 + v2, l3 = l2 + v3;
  sh[t] = l3;
  __syncthreads();
  for (int off = 1; off < 256; off <<= 1) {
    int y = (t >= off) ? sh[t - off] : 0;
    __syncthreads();
    sh[t] += y;
    __syncthreads();
  }
  int excl = sh[t] - l3;
  if (base + 0 < n) out[base + 0] = excl;
  if (base + 1 < n) out[base + 1] = excl + v0;
  if (base + 2 < n) out[base + 2] = excl + l1;
  if (base + 3 < n) out[base + 3] = excl + l2;
  if (t == 255 && bsum) bsum[blockIdx.x] = sh[255];
}

__global__ __launch_bounds__(256) void k_scan_add(
    int* __restrict__ rowptr, int* __restrict__ cursor,
    const int* __restrict__ bscan, int n) {
  int i = blockIdx.x * 256 + threadIdx.x;
  if (i < n) {
    int r = rowptr[i] + bscan[i >> 10];
    rowptr[i] = r;
    cursor[i] = r;
  }
}

__global__ __launch_bounds__(256) void k_fill(
    const int* __restrict__ src, const int* __restrict__ dst,
    int* __restrict__ cursor, int* __restrict__ eidx, int n) {
  int e = blockIdx.x * 256 + threadIdx.x;
  if (e < n) {
    int slot = atomicAdd(&cursor[dst[e]], 1);
    eidx[slot] = src[e];
  }
}

// ================= gather (bf16): aggb[n] = sum_{e: dst=n} xb[src_e] =================
__global__ __launch_bounds__(256) void k_gather(
    const u16* __restrict__ xb, const int* __restrict__ rowptr,
    const int* __restrict__ deg, const int* __restrict__ eidx,
    u16* __restrict__ aggb, int n_nodes) {
  int tid = threadIdx.x;
  int n = blockIdx.x * 16 + (tid >> 4);
  int c = tid & 15;                        // 16B chunk (8 bf16) within the 256B row
  if (n >= n_nodes) return;
  int beg = rowptr[n];
  int dn = deg[n];
  float a0 = 0, a1 = 0, a2 = 0, a3 = 0, a4 = 0, a5 = 0, a6 = 0, a7 = 0;
  for (int i = 0; i < dn; i++) {
    int s = eidx[beg + i];
    uint4 v = *(reinterpret_cast<const uint4*>(xb + (size_t)s * D) + c);
    a0 += bf_lo(v.x); a1 += bf_hi(v.x);
    a2 += bf_lo(v.y); a3 += bf_hi(v.y);
    a4 += bf_lo(v.z); a5 += bf_hi(v.z);
    a6 += bf_lo(v.w); a7 += bf_hi(v.w);
  }
  u32 w0 = rne_bf16(a0) | ((u32)rne_bf16(a1) << 16);
  u32 w1 = rne_bf16(a2) | ((u32)rne_bf16(a3) << 16);
  u32 w2 = rne_bf16(a4) | ((u32)rne_bf16(a5) << 16);
  u32 w3 = rne_bf16(a6) | ((u32)rne_bf16(a7) << 16);
  *(reinterpret_cast<uint4*>(aggb + (size_t)n * D) + c) = make_uint4(w0, w1, w2, w3);
}

// ================= MFMA dual GEMM: out = A1@W1 + A2@W2 + bias (all bf16, f32 acc) =====
// A: [M][128] bf16 row-major. Wt: [128 cols][128 k] bf16 (pre-transposed).
// Block: 256 thr (4 waves), BM=128, full N=128. Wave w -> rows [w*32, w*32+32).
// LDS tiles 128x64 bf16 (A) + 128x64 (Wt), XOR-swizzled: byte ^= (row&7)<<4.
__global__ __launch_bounds__(256) void k_gemm_mfma(
    const u16* __restrict__ A1, const u16* __restrict__ A2,
    const u16* __restrict__ Wt1, const u16* __restrict__ Wt2,
    const float* __restrict__ bias, u16* __restrict__ outp, int M) {
  __shared__ __align__(16) u16 As[128 * 64];
  __shared__ __align__(16) u16 Ws[128 * 64];
  int tid = threadIdx.x;
  int wave = tid >> 6, lane = tid & 63;
  int g = lane >> 4, lr = lane & 15;
  int r0 = blockIdx.x * 128;
  int wr = wave * 32;

  f32x4 acc[2][8];
  #pragma unroll
  for (int fr = 0; fr < 2; fr++)
    #pragma unroll
    for (int fc = 0; fc < 8; fc++)
      acc[fr][fc] = (f32x4){0.f, 0.f, 0.f, 0.f};

  // staging coords (all 256 threads): each thread stages half a row (64B = 4 x 16B)
  int srow = tid >> 1;
  int shalf = tid & 1;

  #pragma unroll 1
  for (int pass = 0; pass < 2; pass++) {
    const u16* A = pass ? A2 : A1;
    const u16* Wt = pass ? Wt2 : Wt1;
    #pragma unroll 1
    for (int kh = 0; kh < 2; kh++) {
      int rg = r0 + srow; if (rg >= M) rg = M - 1;
      const u16* ga = A + (size_t)rg * D + kh * 64 + shalf * 32;
      const u16* gw = Wt + (size_t)srow * D + kh * 64 + shalf * 32;
      #pragma unroll
      for (int cch = 0; cch < 4; cch++) {
        int boff = ((shalf * 64 + cch * 16) ^ ((srow & 7) << 4)) >> 1;  // in u16
        uint4 va = *reinterpret_cast<const uint4*>(ga + cch * 8);
        *reinterpret_cast<uint4*>(&As[srow * 64 + boff]) = va;
        uint4 vw = *reinterpret_cast<const uint4*>(gw + cch * 8);
        *reinterpret_cast<uint4*>(&Ws[srow * 64 + boff]) = vw;
      }
      __syncthreads();
      #pragma unroll
      for (int kc = 0; kc < 2; kc++) {     // k-chunk of 32 within the 64-tile
        int kbyte = kc * 64 + g * 16;      // (k elems)*2 bytes: kc*32*2 + g*8*2
        bf16x8 af[2];
        #pragma unroll
        for (int fr = 0; fr < 2; fr++) {
          int row = wr + fr * 16 + lr;
          int ob = (kbyte ^ ((row & 7) << 4)) >> 1;
          af[fr] = *reinterpret_cast<const bf16x8*>(&As[row * 64 + ob]);
        }
        #pragma unroll
        for (int fc = 0; fc < 8; fc++) {
          int col = fc * 16 + lr;
          int ob = (kbyte ^ ((col & 7) << 4)) >> 1;
          bf16x8 bfv = *reinterpret_cast<const bf16x8*>(&Ws[col * 64 + ob]);
          #pragma unroll
          for (int fr = 0; fr < 2; fr++)
            acc[fr][fc] = __builtin_amdgcn_mfma_f32_16x16x32_bf16(
                af[fr], bfv, acc[fr][fc], 0, 0, 0);
        }
      }
      __syncthreads();
    }
  }

  // epilogue: D[(g*4+j)][lr] per 16x16 frag; add bias, RNE to bf16
  #pragma unroll
  for (int fc = 0; fc < 8; fc++) {
    float bc = bias[fc * 16 + lr];
    #pragma unroll
    for (int fr = 0; fr < 2; fr++) {
      #pragma unroll
      for (int j = 0; j < 4; j++) {
        int R = r0 + wr + fr * 16 + g * 4 + j;
        if (R < M)
          outp[(size_t)R * D + fc * 16 + lr] = rne_bf16(acc[fr][fc][j] + bc);
      }
    }
  }
}

// ================= mean pool (batch sorted, bf16 input) =================
#define CHUNK 256
__global__ __launch_bounds__(256) void k_pool(
    const u16* __restrict__ xb, const int* __restrict__ batch,
    float* __restrict__ pooled, int n_nodes) {
  int col = threadIdx.x & 127;
  int sub = threadIdx.x >> 7;
  int n0 = blockIdx.x * CHUNK;
  int nend = min(n0 + CHUNK, n_nodes);
  float sum = 0.f; int cur = -1;
  for (int n = n0 + sub; n < nend; n += 2) {
    int g = batch[n];
    if (g != cur) {
      if (cur >= 0) atomicAdd(&pooled[cur * D + col], sum);
      sum = 0.f; cur = g;
    }
    sum += __uint_as_float((u32)xb[(size_t)n * D + col] << 16);
  }
  if (cur >= 0) atomicAdd(&pooled[cur * D + col], sum);
}

// ================= counts via sorted-boundary scan =================
__global__ __launch_bounds__(256) void k_bounds(
    const int* __restrict__ batch, int* __restrict__ start, int n) {
  int i = blockIdx.x * 256 + threadIdx.x;
  if (i >= n) return;
  int g = batch[i];
  if (i == 0 || batch[i - 1] != g) start[g] = i;
}

__global__ void k_fin_counts(const int* __restrict__ start,
                             int* __restrict__ counts, int n) {
  int g = threadIdx.x;
  if (g >= NGRAPHS) return;
  int s = start[g];
  int c = 0;
  if (s >= 0) {
    int e = n;
    for (int h = g + 1; h < NGRAPHS; h++)
      if (start[h] >= 0) { e = start[h]; break; }
    c = e - s;
  }
  counts[g] = c;
}

// ================= head =================
__global__ void k_head(const float* __restrict__ pooled, const int* __restrict__ counts,
                       const float* __restrict__ W_fc, const float* __restrict__ b_fc,
                       float* __restrict__ outp) {
  int g = threadIdx.x;
  if (g >= NGRAPHS) return;
  float inv = 1.0f / fmaxf((float)counts[g], 1.0f);
  float logits[NCLASSES];
  #pragma unroll
  for (int j = 0; j < NCLASSES; j++) logits[j] = b_fc[j];
  for (int k = 0; k < D; k++) {
    float p = pooled[g * D + k] * inv;
    #pragma unroll
    for (int j = 0; j < NCLASSES; j++) logits[j] += p * W_fc[k * NCLASSES + j];
  }
  float m = logits[0];
  #pragma unroll
  for (int j = 1; j < NCLASSES; j++) m = fmaxf(m, logits[j]);
  float s = 0.f;
  #pragma unroll
  for (int j = 0; j < NCLASSES; j++) s += expf(logits[j] - m);
  float lse = m + logf(s);
  #pragma unroll
  for (int j = 0; j < NCLASSES; j++) outp[g * NCLASSES + j] = logits[j] - lse;
}

extern "C" void kernel_launch(void* const* d_in, const int* in_sizes, int n_in,
                              void* d_out, int out_size, void* d_ws, size_t ws_size,
                              hipStream_t stream) {
  const float* x      = (const float*)d_in[0];
  const int*   ei     = (const int*)d_in[1];
  const int*   batch  = (const int*)d_in[2];
  const float* W_rel  = (const float*)d_in[3];
  const float* W_root = (const float*)d_in[4];
  const float* b_rel  = (const float*)d_in[5];
  const float* W_fc   = (const float*)d_in[6];
  const float* b_fc   = (const float*)d_in[7];
  float* outp = (float*)d_out;

  int n_nodes = in_sizes[0] / D;
  int n_edges = in_sizes[1] / 2;
  const int* src = ei;
  const int* dst = ei + n_edges;

  char* ws = (char*)d_ws;
  size_t bb = (size_t)n_nodes * D * sizeof(u16);   // 25.6 MB
  size_t nb = (size_t)n_nodes * sizeof(int);
  u16* aggb   = (u16*)(ws);
  u16* xba    = (u16*)(ws + bb);
  u16* xbb    = (u16*)(ws + 2 * bb);
  char* p     = ws + 3 * bb;
  u16* Wt     = (u16*)(p);               p += (size_t)6 * D * D * sizeof(u16);
  int* deg    = (int*)(p);               p += nb;
  int* rowptr = (int*)(p);               p += nb;
  int* cursor = (int*)(p);               p += nb;
  int* bsum   = (int*)(p);               p += 1024 * sizeof(int);
  int* eidx   = (int*)(p);               p += (size_t)n_edges * sizeof(int);
  float* pooled = (float*)(p);           p += (size_t)NGRAPHS * D * sizeof(float);
  int* gstart = (int*)(p);               p += (size_t)NGRAPHS * sizeof(int);
  int* counts = (int*)(p);

  int eblk = (n_edges + 255) / 256;
  int sblk = (n_nodes + 1023) / 1024;

  // prep: weight transpose+cast, x cast
  k_prep_wt<<<(6 * D * D + 255) / 256, 256, 0, stream>>>(W_rel, W_root, Wt);
  long long n8 = (long long)n_nodes * D / 8;
  k_cast0<<<(int)((n8 + 255) / 256), 256, 0, stream>>>(x, xba, n8);

  // CSR build
  hipMemsetAsync(deg, 0, nb, stream);
  k_hist<<<eblk, 256, 0, stream>>>(dst, deg, n_edges);
  k_scan_block<<<sblk, 256, 0, stream>>>(deg, rowptr, bsum, n_nodes);
  k_scan_block<<<1, 256, 0, stream>>>(bsum, bsum, nullptr, sblk);
  k_scan_add<<<(n_nodes + 255) / 256, 256, 0, stream>>>(rowptr, cursor, bsum, n_nodes);
  k_fill<<<eblk, 256, 0, stream>>>(src, dst, cursor, eidx, n_edges);

  // 3 GraphConv layers (bf16 features, MFMA GEMM)
  u16* xc = xba;
  u16* xn = xbb;
  int gemmblk = (n_nodes + 127) / 128;
  for (int l = 0; l < 3; l++) {
    k_gather<<<(n_nodes + 15) / 16, 256, 0, stream>>>(xc, rowptr, deg, eidx, aggb, n_nodes);
    k_gemm_mfma<<<gemmblk, 256, 0, stream>>>(
        aggb, xc, Wt + (size_t)l * D * D, Wt + (size_t)(3 + l) * D * D,
        b_rel + (size_t)l * D, xn, n_nodes);
    u16* t = xc; xc = xn; xn = t;
  }

  // pool + head
  hipMemsetAsync(pooled, 0, (size_t)NGRAPHS * D * sizeof(float), stream);
  hipMemsetAsync(gstart, 0xFF, (size_t)NGRAPHS * sizeof(int), stream);
  k_pool<<<(n_nodes + CHUNK - 1) / CHUNK, 256, 0, stream>>>(xc, batch, pooled, n_nodes);
  k_bounds<<<(n_nodes + 255) / 256, 256, 0, stream>>>(batch, gstart, n_nodes);
  k_fin_counts<<<1, 64, 0, stream>>>(gstart, counts, n_nodes);
  k_head<<<1, 64, 0, stream>>>(pooled, counts, W_fc, b_fc, outp);
}